// Round 6
// baseline (105.861 us; speedup 1.0000x reference)
//
#include <hip/hip_runtime.h>
#include <stdint.h>

#define S_LEN 4096
#define DMODEL 512
#define NHEAD 8
#define DK 64
#define SPLIT 4
#define TBLK 64
#define NT ((S_LEN / SPLIT) / TBLK)  // 16

typedef __attribute__((ext_vector_type(8))) short short8;
typedef __attribute__((ext_vector_type(4))) float f32x4;
typedef __attribute__((ext_vector_type(16))) float f32x16;
typedef __attribute__((ext_vector_type(4))) unsigned int uint4v;
typedef __attribute__((ext_vector_type(2))) unsigned long long ull2;

__device__ __forceinline__ unsigned short f2bf(float f) {
    unsigned int u = __float_as_uint(f);
    u = (u + 0x7fffu + ((u >> 16) & 1u)) >> 16;
    return (unsigned short)u;
}

// async global->LDS, 16B/lane; LDS dest = wave-uniform base + lane*16
__device__ __forceinline__ void gload16(const unsigned short* g, unsigned short* l) {
    __builtin_amdgcn_global_load_lds(
        (const __attribute__((address_space(1))) unsigned int*)g,
        (__attribute__((address_space(3))) unsigned int*)l, 16, 0, 0);
}

// ---------------- prep kernels ----------------

__global__ void cast_bf16_kernel(const float* __restrict__ in,
                                 unsigned short* __restrict__ out, int n4,
                                 float* __restrict__ Z) {
    int i = blockIdx.x * blockDim.x + threadIdx.x;
    if (i == 0) *Z = 0.0f;
    if (i >= n4) return;
    float4 v = reinterpret_cast<const float4*>(in)[i];
    ushort4 o;
    o.x = f2bf(v.x); o.y = f2bf(v.y); o.z = f2bf(v.z); o.w = f2bf(v.w);
    reinterpret_cast<ushort4*>(out)[i] = o;
}

// LDS-tiled transpose+cast: in f32 [h][512][64] -> out bf16 [h][64][512]
__global__ __launch_bounds__(256) void transpose_qkv_kernel(
    const float* __restrict__ wq, const float* __restrict__ wk, const float* __restrict__ wv,
    unsigned short* __restrict__ oq, unsigned short* __restrict__ ok, unsigned short* __restrict__ ov) {
    __shared__ float tile[64][65];
    const int p = blockIdx.y >> 3, h = blockIdx.y & 7;
    const int r0 = blockIdx.x * 64;
    const float* in = ((p == 0) ? wq : (p == 1) ? wk : wv) + (size_t)h * DMODEL * DK;
    unsigned short* out = ((p == 0) ? oq : (p == 1) ? ok : ov) + (size_t)h * DK * DMODEL;
    const int tr = threadIdx.x >> 4, tc4 = (threadIdx.x & 15) * 4;
#pragma unroll
    for (int rr = 0; rr < 4; ++rr) {
        float4 v = *reinterpret_cast<const float4*>(in + (size_t)(r0 + tr + rr * 16) * DK + tc4);
        tile[tr + rr * 16][tc4 + 0] = v.x;
        tile[tr + rr * 16][tc4 + 1] = v.y;
        tile[tr + rr * 16][tc4 + 2] = v.z;
        tile[tr + rr * 16][tc4 + 3] = v.w;
    }
    __syncthreads();
#pragma unroll
    for (int rr = 0; rr < 4; ++rr) {
        const int c = tr + rr * 16;
        ushort4 o;
        o.x = f2bf(tile[tc4 + 0][c]);
        o.y = f2bf(tile[tc4 + 1][c]);
        o.z = f2bf(tile[tc4 + 2][c]);
        o.w = f2bf(tile[tc4 + 3][c]);
        *reinterpret_cast<ushort4*>(out + (size_t)c * DMODEL + r0 + tc4) = o;
    }
}

// wo: f32 [512][512] -> bf16 transposed [512][512]
__global__ __launch_bounds__(256) void transpose_wo_kernel(
    const float* __restrict__ in, unsigned short* __restrict__ out) {
    __shared__ float tile[64][65];
    const int c0 = blockIdx.x * 64, r0 = blockIdx.y * 64;
    const int tr = threadIdx.x >> 4, tc4 = (threadIdx.x & 15) * 4;
#pragma unroll
    for (int rr = 0; rr < 4; ++rr) {
        float4 v = *reinterpret_cast<const float4*>(in + (size_t)(r0 + tr + rr * 16) * DMODEL + c0 + tc4);
        tile[tr + rr * 16][tc4 + 0] = v.x;
        tile[tr + rr * 16][tc4 + 1] = v.y;
        tile[tr + rr * 16][tc4 + 2] = v.z;
        tile[tr + rr * 16][tc4 + 3] = v.w;
    }
    __syncthreads();
#pragma unroll
    for (int rr = 0; rr < 4; ++rr) {
        const int c = tr + rr * 16;
        ushort4 o;
        o.x = f2bf(tile[tc4 + 0][c]);
        o.y = f2bf(tile[tc4 + 1][c]);
        o.z = f2bf(tile[tc4 + 2][c]);
        o.w = f2bf(tile[tc4 + 3][c]);
        *reinterpret_cast<ushort4*>(out + (size_t)(c0 + c) * DMODEL + r0 + tc4) = o;
    }
}

// ---------------- tiled QKV projection GEMM (m97 structure) ----------------
__global__ __launch_bounds__(256, 2) void proj_tiled_kernel(
    const unsigned short* __restrict__ A,
    const unsigned short* __restrict__ BTall,
    unsigned short* __restrict__ Qo,
    unsigned short* __restrict__ Ko,
    unsigned short* __restrict__ Vo) {
    __shared__ unsigned short lds[32768];
    const int tid = threadIdx.x;
    const int w = tid >> 6, l = tid & 63;
    const int l15 = l & 15, lg = l >> 4;
    const int wr = w >> 1, wc = w & 1;
    const int m0 = blockIdx.x * 128, n0 = blockIdx.y * 128;
    const int srow = l >> 3;
    const int schk = ((l & 7) ^ srow) << 3;
    f32x4 acc[4][4] = {};
    {
        unsigned short* ab = &lds[0];
        unsigned short* bb = &lds[8192];
#pragma unroll
        for (int g = 0; g < 4; ++g) {
            gload16(A + (size_t)(m0 + w * 32 + g * 8 + srow) * DMODEL + schk,
                    ab + (w * 32 + g * 8) * 64);
            gload16(BTall + (size_t)(n0 + w * 32 + g * 8 + srow) * DMODEL + schk,
                    bb + (w * 32 + g * 8) * 64);
        }
    }
    __syncthreads();
    for (int kt = 0; kt < 8; ++kt) {
        const int b = (kt & 1) * 16384;
        if (kt + 1 < 8) {
            const int nb = ((kt + 1) & 1) * 16384;
            const int k0 = (kt + 1) * 64;
            unsigned short* ab = &lds[nb];
            unsigned short* bb = &lds[nb + 8192];
#pragma unroll
            for (int g = 0; g < 4; ++g) {
                gload16(A + (size_t)(m0 + w * 32 + g * 8 + srow) * DMODEL + k0 + schk,
                        ab + (w * 32 + g * 8) * 64);
                gload16(BTall + (size_t)(n0 + w * 32 + g * 8 + srow) * DMODEL + k0 + schk,
                        bb + (w * 32 + g * 8) * 64);
            }
        }
#pragma unroll
        for (int kk = 0; kk < 2; ++kk) {
            short8 am[4], bn[4];
#pragma unroll
            for (int mi = 0; mi < 4; ++mi) {
                const int row = wr * 64 + mi * 16 + l15;
                am[mi] = *reinterpret_cast<const short8*>(
                    &lds[b + row * 64 + ((kk * 32 + lg * 8) ^ ((row & 7) << 3))]);
            }
#pragma unroll
            for (int ni = 0; ni < 4; ++ni) {
                const int row = wc * 64 + ni * 16 + l15;
                bn[ni] = *reinterpret_cast<const short8*>(
                    &lds[b + 8192 + row * 64 + ((kk * 32 + lg * 8) ^ ((row & 7) << 3))]);
            }
#pragma unroll
            for (int mi = 0; mi < 4; ++mi)
#pragma unroll
                for (int ni = 0; ni < 4; ++ni)
                    acc[mi][ni] = __builtin_amdgcn_mfma_f32_16x16x32_bf16(am[mi], bn[ni], acc[mi][ni], 0, 0, 0);
        }
        __syncthreads();
    }
#pragma unroll
    for (int ni = 0; ni < 4; ++ni) {
        const int n = n0 + wc * 64 + ni * 16;
        const int p = n >> 9, h = (n >> 6) & 7, vb = n & 63;
        unsigned short* dst = ((p == 0) ? Qo : (p == 1) ? Ko : Vo) + (size_t)h * S_LEN * DK;
        const float sc = (p == 0) ? 0.125f : 1.0f;  // 1/sqrt(64) folded into Q
#pragma unroll
        for (int mi = 0; mi < 4; ++mi) {
            const int s = m0 + wr * 64 + mi * 16 + lg * 4;
#pragma unroll
            for (int r = 0; r < 4; ++r)
                dst[(size_t)(s + r) * DK + vb + l15] = f2bf(acc[mi][ni][r] * sc);
        }
    }
}

// ---------------- tiled output projection GEMM (x 1/Z) ----------------
__global__ __launch_bounds__(256, 2) void out_tiled_kernel(
    const unsigned short* __restrict__ A,
    const unsigned short* __restrict__ BT,
    const float* __restrict__ Z,
    float* __restrict__ Cout) {
    __shared__ unsigned short lds[32768];
    const int tid = threadIdx.x;
    const int w = tid >> 6, l = tid & 63;
    const int l15 = l & 15, lg = l >> 4;
    const int wr = w >> 1, wc = w & 1;
    const int m0 = blockIdx.x * 128, n0 = blockIdx.y * 128;
    const int srow = l >> 3;
    const int schk = ((l & 7) ^ srow) << 3;
    const float invZ = 1.0f / *Z;
    f32x4 acc[4][4] = {};
    {
        unsigned short* ab = &lds[0];
        unsigned short* bb = &lds[8192];
#pragma unroll
        for (int g = 0; g < 4; ++g) {
            gload16(A + (size_t)(m0 + w * 32 + g * 8 + srow) * DMODEL + schk,
                    ab + (w * 32 + g * 8) * 64);
            gload16(BT + (size_t)(n0 + w * 32 + g * 8 + srow) * DMODEL + schk,
                    bb + (w * 32 + g * 8) * 64);
        }
    }
    __syncthreads();
    for (int kt = 0; kt < 8; ++kt) {
        const int b = (kt & 1) * 16384;
        if (kt + 1 < 8) {
            const int nb = ((kt + 1) & 1) * 16384;
            const int k0 = (kt + 1) * 64;
            unsigned short* ab = &lds[nb];
            unsigned short* bb = &lds[nb + 8192];
#pragma unroll
            for (int g = 0; g < 4; ++g) {
                gload16(A + (size_t)(m0 + w * 32 + g * 8 + srow) * DMODEL + k0 + schk,
                        ab + (w * 32 + g * 8) * 64);
                gload16(BT + (size_t)(n0 + w * 32 + g * 8 + srow) * DMODEL + k0 + schk,
                        bb + (w * 32 + g * 8) * 64);
            }
        }
#pragma unroll
        for (int kk = 0; kk < 2; ++kk) {
            short8 am[4], bn[4];
#pragma unroll
            for (int mi = 0; mi < 4; ++mi) {
                const int row = wr * 64 + mi * 16 + l15;
                am[mi] = *reinterpret_cast<const short8*>(
                    &lds[b + row * 64 + ((kk * 32 + lg * 8) ^ ((row & 7) << 3))]);
            }
#pragma unroll
            for (int ni = 0; ni < 4; ++ni) {
                const int row = wc * 64 + ni * 16 + l15;
                bn[ni] = *reinterpret_cast<const short8*>(
                    &lds[b + 8192 + row * 64 + ((kk * 32 + lg * 8) ^ ((row & 7) << 3))]);
            }
#pragma unroll
            for (int mi = 0; mi < 4; ++mi)
#pragma unroll
                for (int ni = 0; ni < 4; ++ni)
                    acc[mi][ni] = __builtin_amdgcn_mfma_f32_16x16x32_bf16(am[mi], bn[ni], acc[mi][ni], 0, 0, 0);
        }
        __syncthreads();
    }
#pragma unroll
    for (int ni = 0; ni < 4; ++ni) {
        const int n = n0 + wc * 64 + ni * 16;
#pragma unroll
        for (int mi = 0; mi < 4; ++mi) {
            const int s = m0 + wr * 64 + mi * 16 + lg * 4;
#pragma unroll
            for (int r = 0; r < 4; ++r)
                Cout[(size_t)(s + r) * DMODEL + n + l15] = acc[mi][ni][r] * invZ;
        }
    }
}

// ---------------- V transpose: Vb[h][t][v] -> VT[h][v][t] ----------------
__global__ __launch_bounds__(256) void vt_kernel(const unsigned short* __restrict__ Vb,
                                                 unsigned short* __restrict__ VT) {
    __shared__ unsigned short tile[4096];
    int h = blockIdx.y, t0 = blockIdx.x * 64;
    const unsigned short* Vh = Vb + h * (S_LEN * DK);
    unsigned short* VTh = VT + h * (DK * S_LEN);
    int c8 = (threadIdx.x & 7) * 8, rw = threadIdx.x >> 3;
#pragma unroll
    for (int rr = 0; rr < 2; ++rr) {
        int t = rw + rr * 32;
        short8 v = *reinterpret_cast<const short8*>(Vh + (t0 + t) * DK + c8);
        *reinterpret_cast<short8*>(&tile[t * 64 + (c8 ^ ((t & 7) << 3))]) = v;
    }
    __syncthreads();
#pragma unroll
    for (int rr = 0; rr < 2; ++rr) {
        int v = rw + rr * 32;
        short8 s;
#pragma unroll
        for (int i = 0; i < 8; ++i) {
            int t = c8 + i;
            s[i] = (short)tile[t * 64 + (v ^ ((t & 7) << 3))];
        }
        *reinterpret_cast<short8*>(VTh + v * S_LEN + t0 + c8) = s;
    }
}

// ---------------- fused attention (unnormalized, split over t) ----------------
// 4 waves x 64 q = 256 q/block; t tiled by 64. Swapped QK^T, P in-register.
// T3/T4 pipeline: 4 LDS buffers, depth-2 prefetch, ONE raw s_barrier per tile,
// counted s_waitcnt vmcnt (8 steady / 4 / 0 tail) -- no vmcnt(0) drain in loop.
__device__ __forceinline__ void make_pfrag(const f32x16& s, short8 pf[2],
                                           float& z0, float& z1) {
    float p[16];
#pragma unroll
    for (int r = 0; r < 16; ++r) p[r] = __expf(s[r]);
#pragma unroll
    for (int r = 0; r < 16; r += 2) { z0 += p[r]; z1 += p[r + 1]; }
    unsigned int c[8];
#pragma unroll
    for (int j = 0; j < 8; ++j)
        asm("v_cvt_pk_bf16_f32 %0, %1, %2" : "=v"(c[j]) : "v"(p[2 * j]), "v"(p[2 * j + 1]));
    uint4v wa = {c[0], c[1], c[2], c[3]};
    uint4v wb = {c[4], c[5], c[6], c[7]};
    pf[0] = __builtin_bit_cast(short8, wa);
    pf[1] = __builtin_bit_cast(short8, wb);
}

__global__ __launch_bounds__(256, 2) void attn_kernel(
    const unsigned short* __restrict__ Qg,
    const unsigned short* __restrict__ Kg,
    const unsigned short* __restrict__ VTg,
    float* __restrict__ Opart,
    float* __restrict__ Z) {
    __shared__ unsigned short lds[32768];  // 4 bufs x (K[64][64] + VT[64][64]) = 64KB
    const int tid = threadIdx.x;
    const int w = tid >> 6, l = tid & 63;
    const int l31 = l & 31, lh = l >> 5;
    const int qb = blockIdx.x, h = blockIdx.y, sp = blockIdx.z;
    const unsigned short* Qh = Qg + h * (S_LEN * DK);
    const unsigned short* Kh = Kg + h * (S_LEN * DK);
    const unsigned short* VTh = VTg + h * (DK * S_LEN);
    const int t_base = sp * (S_LEN / SPLIT);
    const int q0 = qb * 256 + w * 64;

    short8 bq[2][4];
#pragma unroll
    for (int qc = 0; qc < 2; ++qc)
#pragma unroll
        for (int ks = 0; ks < 4; ++ks)
            bq[qc][ks] = *reinterpret_cast<const short8*>(
                Qh + (q0 + qc * 32 + l31) * DK + ks * 16 + lh * 8);

    f32x16 oacc[2][2] = {};
    float z0 = 0.0f, z1 = 0.0f;

    // staging lane roles (pre-swizzled global source, linear LDS dest)
    const int srow = l >> 3;
    const int scol = ((l & 7) ^ srow) << 3;
    const unsigned short* gkb = Kh + (size_t)(t_base + w * 16 + srow) * DK + scol;
    const unsigned short* gvb = VTh + (size_t)(w * 16 + srow) * S_LEN + t_base + scol;

    // stage tile tt -> buf (tt&3): 4 gload16 per wave (2 K + 2 VT)
    auto stage = [&](int tt) {
        const int boff = (tt & 3) * 8192;
        unsigned short* kb = &lds[boff + w * 1024];
        unsigned short* vb = &lds[boff + 4096 + w * 1024];
        gload16(gkb + (size_t)tt * TBLK * DK, kb);
        gload16(gkb + (size_t)tt * TBLK * DK + 8 * DK, kb + 512);
        gload16(gvb + tt * TBLK, vb);
        gload16(gvb + tt * TBLK + 8 * S_LEN, vb + 512);
    };

    stage(0);
    stage(1);
    for (int it = 0; it < NT; ++it) {
        if (it + 2 < NT) stage(it + 2);
        // retire tile it's 4 loads; keep tiles it+1, it+2 in flight across barrier
        if (it < NT - 2)       asm volatile("s_waitcnt vmcnt(8)" ::: "memory");
        else if (it == NT - 2) asm volatile("s_waitcnt vmcnt(4)" ::: "memory");
        else                   asm volatile("s_waitcnt vmcnt(0)" ::: "memory");
        __builtin_amdgcn_s_barrier();
        const int b = (it & 3) * 8192;
#pragma unroll
        for (int tc = 0; tc < 2; ++tc) {
            f32x16 s0 = {}, s1 = {};
            const int tA = tc * 32 + l31;
            __builtin_amdgcn_s_setprio(1);
#pragma unroll
            for (int ks = 0; ks < 4; ++ks) {
                short8 ka = *reinterpret_cast<const short8*>(
                    &lds[b + tA * 64 + ((ks * 16 + lh * 8) ^ ((tA & 7) << 3))]);
                s0 = __builtin_amdgcn_mfma_f32_32x32x16_bf16(ka, bq[0][ks], s0, 0, 0, 0);
                s1 = __builtin_amdgcn_mfma_f32_32x32x16_bf16(ka, bq[1][ks], s1, 0, 0, 0);
            }
            __builtin_amdgcn_s_setprio(0);
            short8 pf0[2], pf1[2];
            make_pfrag(s0, pf0, z0, z1);
            make_pfrag(s1, pf1, z0, z1);
            __builtin_amdgcn_s_setprio(1);
#pragma unroll
            for (int sub = 0; sub < 2; ++sub) {
#pragma unroll
                for (int vc = 0; vc < 2; ++vc) {
                    const int vx = l31 & 7;
                    const int cc = tc * 4 + sub * 2;
                    const int base = b + 4096 + (vc * 32 + l31) * 64;
                    unsigned long long d0 = *reinterpret_cast<const unsigned long long*>(
                        &lds[base + ((cc ^ vx) << 3) + lh * 4]);
                    unsigned long long d1 = *reinterpret_cast<const unsigned long long*>(
                        &lds[base + (((cc + 1) ^ vx) << 3) + lh * 4]);
                    ull2 dd = {d0, d1};
                    short8 bv = __builtin_bit_cast(short8, dd);
                    oacc[0][vc] = __builtin_amdgcn_mfma_f32_32x32x16_bf16(pf0[sub], bv, oacc[0][vc], 0, 0, 0);
                    oacc[1][vc] = __builtin_amdgcn_mfma_f32_32x32x16_bf16(pf1[sub], bv, oacc[1][vc], 0, 0, 0);
                }
            }
            __builtin_amdgcn_s_setprio(0);
        }
    }
    float* Op = Opart + ((size_t)(sp * NHEAD + h) * S_LEN + q0) * DK;
#pragma unroll
    for (int qc = 0; qc < 2; ++qc)
#pragma unroll
        for (int vc = 0; vc < 2; ++vc)
#pragma unroll
            for (int reg = 0; reg < 16; ++reg) {
                int q = qc * 32 + (reg & 3) + 8 * (reg >> 2) + 4 * lh;
                Op[(size_t)q * DK + vc * 32 + l31] = oacc[qc][vc][reg];
            }
    float zloc = z0 + z1;
#pragma unroll
    for (int off = 32; off > 0; off >>= 1) zloc += __shfl_xor(zloc, off, 64);
    if (l == 0) atomicAdd(Z, zloc);
}

// ---------------- split reduction: sum partials -> bf16 concat ----------------
__global__ __launch_bounds__(256) void reduce_o_kernel(
    const float* __restrict__ Opart, unsigned short* __restrict__ cc) {
    const int HSV = NHEAD * S_LEN * DK;
    int i = blockIdx.x * blockDim.x + threadIdx.x;
    if (i * 4 >= HSV) return;
    f32x4 s = {};
#pragma unroll
    for (int sp = 0; sp < SPLIT; ++sp) {
        f32x4 v = *reinterpret_cast<const f32x4*>(&Opart[(size_t)sp * HSV + i * 4]);
        s += v;
    }
    int e = i * 4;
    int h = e / (S_LEN * DK);
    int rem = e - h * (S_LEN * DK);
    int srow = rem / DK;
    int v = rem - srow * DK;
    ushort4 o4;
    o4.x = f2bf(s[0]); o4.y = f2bf(s[1]); o4.z = f2bf(s[2]); o4.w = f2bf(s[3]);
    *reinterpret_cast<ushort4*>(&cc[srow * DMODEL + h * DK + v]) = o4;
}

// ---------------- launcher ----------------

extern "C" void kernel_launch(void* const* d_in, const int* in_sizes, int n_in,
                              void* d_out, int out_size, void* d_ws, size_t ws_size,
                              hipStream_t stream) {
    const float* emb = (const float*)d_in[0];
    const float* wq = (const float*)d_in[1];
    const float* wk = (const float*)d_in[2];
    const float* wv = (const float*)d_in[3];
    const float* wo = (const float*)d_in[4];
    float* out = (float*)d_out;
    char* ws = (char*)d_ws;
    unsigned short* embB = (unsigned short*)(ws);             // 4 MB (reused as VT)
    unsigned short* wqT  = (unsigned short*)(ws + 4194304);   // contiguous 3 x 512 KB
    unsigned short* wkT  = (unsigned short*)(ws + 4718592);
    unsigned short* wvT  = (unsigned short*)(ws + 5242880);
    unsigned short* woT  = (unsigned short*)(ws + 5767168);
    unsigned short* Qb   = (unsigned short*)(ws + 6291456);   // 4 MB each
    unsigned short* Kb   = (unsigned short*)(ws + 10485760);
    unsigned short* Vb   = (unsigned short*)(ws + 14680064);
    unsigned short* cc   = (unsigned short*)(ws + 18874368);  // 4 MB
    float* Z             = (float*)(ws + 23068672);
    float* Opart         = (float*)(ws + 23072768);           // 32 MB
    unsigned short* VT   = embB;  // embB dead after proj

    cast_bf16_kernel<<<2048, 256, 0, stream>>>(emb, embB, 524288, Z);
    transpose_qkv_kernel<<<dim3(8, 24), 256, 0, stream>>>(wq, wk, wv, wqT, wkT, wvT);
    transpose_wo_kernel<<<dim3(8, 8), 256, 0, stream>>>(wo, woT);
    proj_tiled_kernel<<<dim3(32, 12), 256, 0, stream>>>(embB, wqT, Qb, Kb, Vb);
    vt_kernel<<<dim3(64, 8), 256, 0, stream>>>(Vb, VT);
    attn_kernel<<<dim3(16, 8, SPLIT), 256, 0, stream>>>(Qb, Kb, VT, Opart, Z);
    reduce_o_kernel<<<2048, 256, 0, stream>>>(Opart, cc);
    out_tiled_kernel<<<dim3(32, 4), 256, 0, stream>>>(cc, woT, Z, out);
}

// Round 7
// 100.586 us; speedup vs baseline: 1.0524x; 1.0524x over previous
//
#include <hip/hip_runtime.h>
#include <stdint.h>

#define S_LEN 4096
#define DMODEL 512
#define NHEAD 8
#define DK 64
#define SPLIT 4
#define TBLK 64
#define NT ((S_LEN / SPLIT) / TBLK)  // 16

#if __has_builtin(__builtin_amdgcn_exp2f)
#define EXPFN(x) __builtin_amdgcn_exp2f(x)
#define QSCALE 0.18033688011112042f  // 0.125 * log2(e): exp(S) = exp2(S')
#else
#define EXPFN(x) __expf(x)
#define QSCALE 0.125f
#endif

typedef __attribute__((ext_vector_type(8))) short short8;
typedef __attribute__((ext_vector_type(4))) float f32x4;
typedef __attribute__((ext_vector_type(16))) float f32x16;
typedef __attribute__((ext_vector_type(4))) unsigned int uint4v;
typedef __attribute__((ext_vector_type(2))) unsigned long long ull2;

__device__ __forceinline__ unsigned short f2bf(float f) {
    unsigned int u = __float_as_uint(f);
    u = (u + 0x7fffu + ((u >> 16) & 1u)) >> 16;
    return (unsigned short)u;
}

// async global->LDS, 16B/lane; LDS dest = wave-uniform base + lane*16
__device__ __forceinline__ void gload16(const unsigned short* g, unsigned short* l) {
    __builtin_amdgcn_global_load_lds(
        (const __attribute__((address_space(1))) unsigned int*)g,
        (__attribute__((address_space(3))) unsigned int*)l, 16, 0, 0);
}

// ---------------- prep kernels ----------------

__global__ void cast_bf16_kernel(const float* __restrict__ in,
                                 unsigned short* __restrict__ out, int n4,
                                 float* __restrict__ Z) {
    int i = blockIdx.x * blockDim.x + threadIdx.x;
    if (i == 0) *Z = 0.0f;
    if (i >= n4) return;
    float4 v = reinterpret_cast<const float4*>(in)[i];
    ushort4 o;
    o.x = f2bf(v.x); o.y = f2bf(v.y); o.z = f2bf(v.z); o.w = f2bf(v.w);
    reinterpret_cast<ushort4*>(out)[i] = o;
}

// LDS-tiled transpose+cast: in f32 [h][512][64] -> out bf16 [h][64][512]
__global__ __launch_bounds__(256) void transpose_qkv_kernel(
    const float* __restrict__ wq, const float* __restrict__ wk, const float* __restrict__ wv,
    unsigned short* __restrict__ oq, unsigned short* __restrict__ ok, unsigned short* __restrict__ ov) {
    __shared__ float tile[64][65];
    const int p = blockIdx.y >> 3, h = blockIdx.y & 7;
    const int r0 = blockIdx.x * 64;
    const float* in = ((p == 0) ? wq : (p == 1) ? wk : wv) + (size_t)h * DMODEL * DK;
    unsigned short* out = ((p == 0) ? oq : (p == 1) ? ok : ov) + (size_t)h * DK * DMODEL;
    const int tr = threadIdx.x >> 4, tc4 = (threadIdx.x & 15) * 4;
#pragma unroll
    for (int rr = 0; rr < 4; ++rr) {
        float4 v = *reinterpret_cast<const float4*>(in + (size_t)(r0 + tr + rr * 16) * DK + tc4);
        tile[tr + rr * 16][tc4 + 0] = v.x;
        tile[tr + rr * 16][tc4 + 1] = v.y;
        tile[tr + rr * 16][tc4 + 2] = v.z;
        tile[tr + rr * 16][tc4 + 3] = v.w;
    }
    __syncthreads();
#pragma unroll
    for (int rr = 0; rr < 4; ++rr) {
        const int c = tr + rr * 16;
        ushort4 o;
        o.x = f2bf(tile[tc4 + 0][c]);
        o.y = f2bf(tile[tc4 + 1][c]);
        o.z = f2bf(tile[tc4 + 2][c]);
        o.w = f2bf(tile[tc4 + 3][c]);
        *reinterpret_cast<ushort4*>(out + (size_t)c * DMODEL + r0 + tc4) = o;
    }
}

// wo: f32 [512][512] -> bf16 transposed [512][512]
__global__ __launch_bounds__(256) void transpose_wo_kernel(
    const float* __restrict__ in, unsigned short* __restrict__ out) {
    __shared__ float tile[64][65];
    const int c0 = blockIdx.x * 64, r0 = blockIdx.y * 64;
    const int tr = threadIdx.x >> 4, tc4 = (threadIdx.x & 15) * 4;
#pragma unroll
    for (int rr = 0; rr < 4; ++rr) {
        float4 v = *reinterpret_cast<const float4*>(in + (size_t)(r0 + tr + rr * 16) * DMODEL + c0 + tc4);
        tile[tr + rr * 16][tc4 + 0] = v.x;
        tile[tr + rr * 16][tc4 + 1] = v.y;
        tile[tr + rr * 16][tc4 + 2] = v.z;
        tile[tr + rr * 16][tc4 + 3] = v.w;
    }
    __syncthreads();
#pragma unroll
    for (int rr = 0; rr < 4; ++rr) {
        const int c = tr + rr * 16;
        ushort4 o;
        o.x = f2bf(tile[tc4 + 0][c]);
        o.y = f2bf(tile[tc4 + 1][c]);
        o.z = f2bf(tile[tc4 + 2][c]);
        o.w = f2bf(tile[tc4 + 3][c]);
        *reinterpret_cast<ushort4*>(out + (size_t)(c0 + c) * DMODEL + r0 + tc4) = o;
    }
}

// ---------------- tiled QKV projection GEMM (m97 structure) ----------------
__global__ __launch_bounds__(256, 2) void proj_tiled_kernel(
    const unsigned short* __restrict__ A,
    const unsigned short* __restrict__ BTall,
    unsigned short* __restrict__ Qo,
    unsigned short* __restrict__ Ko,
    unsigned short* __restrict__ Vo) {
    __shared__ unsigned short lds[32768];
    const int tid = threadIdx.x;
    const int w = tid >> 6, l = tid & 63;
    const int l15 = l & 15, lg = l >> 4;
    const int wr = w >> 1, wc = w & 1;
    const int m0 = blockIdx.x * 128, n0 = blockIdx.y * 128;
    const int srow = l >> 3;
    const int schk = ((l & 7) ^ srow) << 3;
    f32x4 acc[4][4] = {};
    {
        unsigned short* ab = &lds[0];
        unsigned short* bb = &lds[8192];
#pragma unroll
        for (int g = 0; g < 4; ++g) {
            gload16(A + (size_t)(m0 + w * 32 + g * 8 + srow) * DMODEL + schk,
                    ab + (w * 32 + g * 8) * 64);
            gload16(BTall + (size_t)(n0 + w * 32 + g * 8 + srow) * DMODEL + schk,
                    bb + (w * 32 + g * 8) * 64);
        }
    }
    __syncthreads();
    for (int kt = 0; kt < 8; ++kt) {
        const int b = (kt & 1) * 16384;
        if (kt + 1 < 8) {
            const int nb = ((kt + 1) & 1) * 16384;
            const int k0 = (kt + 1) * 64;
            unsigned short* ab = &lds[nb];
            unsigned short* bb = &lds[nb + 8192];
#pragma unroll
            for (int g = 0; g < 4; ++g) {
                gload16(A + (size_t)(m0 + w * 32 + g * 8 + srow) * DMODEL + k0 + schk,
                        ab + (w * 32 + g * 8) * 64);
                gload16(BTall + (size_t)(n0 + w * 32 + g * 8 + srow) * DMODEL + k0 + schk,
                        bb + (w * 32 + g * 8) * 64);
            }
        }
#pragma unroll
        for (int kk = 0; kk < 2; ++kk) {
            short8 am[4], bn[4];
#pragma unroll
            for (int mi = 0; mi < 4; ++mi) {
                const int row = wr * 64 + mi * 16 + l15;
                am[mi] = *reinterpret_cast<const short8*>(
                    &lds[b + row * 64 + ((kk * 32 + lg * 8) ^ ((row & 7) << 3))]);
            }
#pragma unroll
            for (int ni = 0; ni < 4; ++ni) {
                const int row = wc * 64 + ni * 16 + l15;
                bn[ni] = *reinterpret_cast<const short8*>(
                    &lds[b + 8192 + row * 64 + ((kk * 32 + lg * 8) ^ ((row & 7) << 3))]);
            }
#pragma unroll
            for (int mi = 0; mi < 4; ++mi)
#pragma unroll
                for (int ni = 0; ni < 4; ++ni)
                    acc[mi][ni] = __builtin_amdgcn_mfma_f32_16x16x32_bf16(am[mi], bn[ni], acc[mi][ni], 0, 0, 0);
        }
        __syncthreads();
    }
#pragma unroll
    for (int ni = 0; ni < 4; ++ni) {
        const int n = n0 + wc * 64 + ni * 16;
        const int p = n >> 9, h = (n >> 6) & 7, vb = n & 63;
        unsigned short* dst = ((p == 0) ? Qo : (p == 1) ? Ko : Vo) + (size_t)h * S_LEN * DK;
        const float sc = (p == 0) ? QSCALE : 1.0f;
#pragma unroll
        for (int mi = 0; mi < 4; ++mi) {
            const int s = m0 + wr * 64 + mi * 16 + lg * 4;
#pragma unroll
            for (int r = 0; r < 4; ++r)
                dst[(size_t)(s + r) * DK + vb + l15] = f2bf(acc[mi][ni][r] * sc);
        }
    }
}

// ---------------- tiled output projection GEMM (x 1/Z) ----------------
__global__ __launch_bounds__(256, 2) void out_tiled_kernel(
    const unsigned short* __restrict__ A,
    const unsigned short* __restrict__ BT,
    const float* __restrict__ Z,
    float* __restrict__ Cout) {
    __shared__ unsigned short lds[32768];
    const int tid = threadIdx.x;
    const int w = tid >> 6, l = tid & 63;
    const int l15 = l & 15, lg = l >> 4;
    const int wr = w >> 1, wc = w & 1;
    const int m0 = blockIdx.x * 128, n0 = blockIdx.y * 128;
    const int srow = l >> 3;
    const int schk = ((l & 7) ^ srow) << 3;
    const float invZ = 1.0f / *Z;
    f32x4 acc[4][4] = {};
    {
        unsigned short* ab = &lds[0];
        unsigned short* bb = &lds[8192];
#pragma unroll
        for (int g = 0; g < 4; ++g) {
            gload16(A + (size_t)(m0 + w * 32 + g * 8 + srow) * DMODEL + schk,
                    ab + (w * 32 + g * 8) * 64);
            gload16(BT + (size_t)(n0 + w * 32 + g * 8 + srow) * DMODEL + schk,
                    bb + (w * 32 + g * 8) * 64);
        }
    }
    __syncthreads();
    for (int kt = 0; kt < 8; ++kt) {
        const int b = (kt & 1) * 16384;
        if (kt + 1 < 8) {
            const int nb = ((kt + 1) & 1) * 16384;
            const int k0 = (kt + 1) * 64;
            unsigned short* ab = &lds[nb];
            unsigned short* bb = &lds[nb + 8192];
#pragma unroll
            for (int g = 0; g < 4; ++g) {
                gload16(A + (size_t)(m0 + w * 32 + g * 8 + srow) * DMODEL + k0 + schk,
                        ab + (w * 32 + g * 8) * 64);
                gload16(BT + (size_t)(n0 + w * 32 + g * 8 + srow) * DMODEL + k0 + schk,
                        bb + (w * 32 + g * 8) * 64);
            }
        }
#pragma unroll
        for (int kk = 0; kk < 2; ++kk) {
            short8 am[4], bn[4];
#pragma unroll
            for (int mi = 0; mi < 4; ++mi) {
                const int row = wr * 64 + mi * 16 + l15;
                am[mi] = *reinterpret_cast<const short8*>(
                    &lds[b + row * 64 + ((kk * 32 + lg * 8) ^ ((row & 7) << 3))]);
            }
#pragma unroll
            for (int ni = 0; ni < 4; ++ni) {
                const int row = wc * 64 + ni * 16 + l15;
                bn[ni] = *reinterpret_cast<const short8*>(
                    &lds[b + 8192 + row * 64 + ((kk * 32 + lg * 8) ^ ((row & 7) << 3))]);
            }
#pragma unroll
            for (int mi = 0; mi < 4; ++mi)
#pragma unroll
                for (int ni = 0; ni < 4; ++ni)
                    acc[mi][ni] = __builtin_amdgcn_mfma_f32_16x16x32_bf16(am[mi], bn[ni], acc[mi][ni], 0, 0, 0);
        }
        __syncthreads();
    }
#pragma unroll
    for (int ni = 0; ni < 4; ++ni) {
        const int n = n0 + wc * 64 + ni * 16;
#pragma unroll
        for (int mi = 0; mi < 4; ++mi) {
            const int s = m0 + wr * 64 + mi * 16 + lg * 4;
#pragma unroll
            for (int r = 0; r < 4; ++r)
                Cout[(size_t)(s + r) * DMODEL + n + l15] = acc[mi][ni][r] * invZ;
        }
    }
}

// ---------------- V transpose: Vb[h][t][v] -> VT[h][v][t] ----------------
__global__ __launch_bounds__(256) void vt_kernel(const unsigned short* __restrict__ Vb,
                                                 unsigned short* __restrict__ VT) {
    __shared__ unsigned short tile[4096];
    int h = blockIdx.y, t0 = blockIdx.x * 64;
    const unsigned short* Vh = Vb + h * (S_LEN * DK);
    unsigned short* VTh = VT + h * (DK * S_LEN);
    int c8 = (threadIdx.x & 7) * 8, rw = threadIdx.x >> 3;
#pragma unroll
    for (int rr = 0; rr < 2; ++rr) {
        int t = rw + rr * 32;
        short8 v = *reinterpret_cast<const short8*>(Vh + (t0 + t) * DK + c8);
        *reinterpret_cast<short8*>(&tile[t * 64 + (c8 ^ ((t & 7) << 3))]) = v;
    }
    __syncthreads();
#pragma unroll
    for (int rr = 0; rr < 2; ++rr) {
        int v = rw + rr * 32;
        short8 s;
#pragma unroll
        for (int i = 0; i < 8; ++i) {
            int t = c8 + i;
            s[i] = (short)tile[t * 64 + (v ^ ((t & 7) << 3))];
        }
        *reinterpret_cast<short8*>(VTh + v * S_LEN + t0 + c8) = s;
    }
}

// ---------------- fused attention (unnormalized, split over t) ----------------
// Deferred-PV software pipeline: step t = QK^T(t) -> { exp(t)  ||  PV(t-1) }.
// exp (VALU) has no nearby consumer; PV(t-1) MFMAs interleave with it.
// 4 LDS bufs, stage AFTER barrier (overwrites buf t-2, all readers done),
// steady-state vmcnt(4). P-fragments ping-pong pfA/pfB (static indexing).
__device__ __forceinline__ void make_pfrag(const f32x16& s, short8 pf[2],
                                           float& z0, float& z1) {
    float p[16];
#pragma unroll
    for (int r = 0; r < 16; ++r) p[r] = EXPFN(s[r]);
#pragma unroll
    for (int r = 0; r < 16; r += 2) { z0 += p[r]; z1 += p[r + 1]; }
    unsigned int c[8];
#pragma unroll
    for (int j = 0; j < 8; ++j)
        asm("v_cvt_pk_bf16_f32 %0, %1, %2" : "=v"(c[j]) : "v"(p[2 * j]), "v"(p[2 * j + 1]));
    uint4v wa = {c[0], c[1], c[2], c[3]};
    uint4v wb = {c[4], c[5], c[6], c[7]};
    pf[0] = __builtin_bit_cast(short8, wa);
    pf[1] = __builtin_bit_cast(short8, wb);
}

#define QK_TC(BC, TC, SD0, SD1)                                                       \
    {                                                                                 \
        const int tA_ = (TC) * 32 + l31;                                              \
        __builtin_amdgcn_s_setprio(1);                                                \
        _Pragma("unroll") for (int ks_ = 0; ks_ < 4; ++ks_) {                         \
            short8 ka_ = *reinterpret_cast<const short8*>(                            \
                &lds[(BC) + tA_ * 64 + ((ks_ * 16 + lh * 8) ^ ((tA_ & 7) << 3))]);    \
            SD0 = __builtin_amdgcn_mfma_f32_32x32x16_bf16(ka_, bq[0][ks_], SD0, 0, 0, 0); \
            SD1 = __builtin_amdgcn_mfma_f32_32x32x16_bf16(ka_, bq[1][ks_], SD1, 0, 0, 0); \
        }                                                                             \
        __builtin_amdgcn_s_setprio(0);                                                \
    }

#define PV_HALF(BP, TCP, PFO)                                                         \
    _Pragma("unroll") for (int sub_ = 0; sub_ < 2; ++sub_)                            \
    _Pragma("unroll") for (int vc_ = 0; vc_ < 2; ++vc_) {                             \
        const int cc_ = (TCP) * 4 + sub_ * 2;                                         \
        const int base_ = (BP) + 4096 + (vc_ * 32 + l31) * 64;                        \
        unsigned long long d0_ = *reinterpret_cast<const unsigned long long*>(        \
            &lds[base_ + ((cc_ ^ vx) << 3) + lh * 4]);                                \
        unsigned long long d1_ = *reinterpret_cast<const unsigned long long*>(        \
            &lds[base_ + (((cc_ + 1) ^ vx) << 3) + lh * 4]);                          \
        ull2 dd_ = {d0_, d1_};                                                        \
        short8 bv_ = __builtin_bit_cast(short8, dd_);                                 \
        oacc[0][vc_] = __builtin_amdgcn_mfma_f32_32x32x16_bf16(PFO[TCP][0][sub_], bv_, oacc[0][vc_], 0, 0, 0); \
        oacc[1][vc_] = __builtin_amdgcn_mfma_f32_32x32x16_bf16(PFO[TCP][1][sub_], bv_, oacc[1][vc_], 0, 0, 0); \
    }

// steady step: retire tile T, stage T+2, QK(T)+exp(T) interleaved with PV(T-1)
#define STEP_CORE(T, PFN, PFO)                                                        \
    {                                                                                 \
        if ((T) + 2 < NT) stage((T) + 2);                                             \
        const int bC_ = ((T) & 3) * 8192;                                             \
        const int bP_ = (((T) + 3) & 3) * 8192;                                       \
        f32x16 sA_ = {}, sB_ = {};                                                    \
        QK_TC(bC_, 0, sA_, sB_);                                                      \
        make_pfrag(sA_, PFN[0][0], z0, z1);                                           \
        PV_HALF(bP_, 0, PFO);                                                         \
        make_pfrag(sB_, PFN[0][1], z0, z1);                                           \
        f32x16 sC_ = {}, sD_ = {};                                                    \
        QK_TC(bC_, 1, sC_, sD_);                                                      \
        make_pfrag(sC_, PFN[1][0], z0, z1);                                           \
        PV_HALF(bP_, 1, PFO);                                                         \
        make_pfrag(sD_, PFN[1][1], z0, z1);                                           \
    }

__global__ __launch_bounds__(256, 2) void attn_kernel(
    const unsigned short* __restrict__ Qg,
    const unsigned short* __restrict__ Kg,
    const unsigned short* __restrict__ VTg,
    float* __restrict__ Opart,
    float* __restrict__ Z) {
    __shared__ unsigned short lds[32768];  // 4 bufs x (K[64][64] + VT[64][64]) = 64KB
    const int tid = threadIdx.x;
    const int w = tid >> 6, l = tid & 63;
    const int l31 = l & 31, lh = l >> 5;
    const int vx = l31 & 7;
    const int qb = blockIdx.x, h = blockIdx.y, sp = blockIdx.z;
    const unsigned short* Qh = Qg + h * (S_LEN * DK);
    const unsigned short* Kh = Kg + h * (S_LEN * DK);
    const unsigned short* VTh = VTg + h * (DK * S_LEN);
    const int t_base = sp * (S_LEN / SPLIT);
    const int q0 = qb * 256 + w * 64;

    short8 bq[2][4];
#pragma unroll
    for (int qc = 0; qc < 2; ++qc)
#pragma unroll
        for (int ks = 0; ks < 4; ++ks)
            bq[qc][ks] = *reinterpret_cast<const short8*>(
                Qh + (q0 + qc * 32 + l31) * DK + ks * 16 + lh * 8);

    f32x16 oacc[2][2] = {};
    float z0 = 0.0f, z1 = 0.0f;
    short8 pfA[2][2][2], pfB[2][2][2];  // [tc][q][sub]

    // staging lane roles (pre-swizzled global source, linear LDS dest)
    const int srow = l >> 3;
    const int scol = ((l & 7) ^ srow) << 3;
    const unsigned short* gkb = Kh + (size_t)(t_base + w * 16 + srow) * DK + scol;
    const unsigned short* gvb = VTh + (size_t)(w * 16 + srow) * S_LEN + t_base + scol;

    auto stage = [&](int tt) {
        const int boff = (tt & 3) * 8192;
        unsigned short* kb = &lds[boff + w * 1024];
        unsigned short* vb = &lds[boff + 4096 + w * 1024];
        gload16(gkb + (size_t)tt * TBLK * DK, kb);
        gload16(gkb + (size_t)tt * TBLK * DK + 8 * DK, kb + 512);
        gload16(gvb + tt * TBLK, vb);
        gload16(gvb + tt * TBLK + 8 * S_LEN, vb + 512);
    };

    stage(0);
    stage(1);
    // ---- step 0: QK+exp only (no PV yet) ----
    asm volatile("s_waitcnt vmcnt(4)" ::: "memory");
    __builtin_amdgcn_s_barrier();
    {
        stage(2);
        f32x16 sA_ = {}, sB_ = {};
        QK_TC(0, 0, sA_, sB_);
        make_pfrag(sA_, pfA[0][0], z0, z1);
        make_pfrag(sB_, pfA[0][1], z0, z1);
        f32x16 sC_ = {}, sD_ = {};
        QK_TC(0, 1, sC_, sD_);
        make_pfrag(sC_, pfA[1][0], z0, z1);
        make_pfrag(sD_, pfA[1][1], z0, z1);
    }
    // ---- steps 1..14 (steady state) ----
    for (int tp = 0; tp < 7; ++tp) {
        const int t1 = 2 * tp + 1;
        asm volatile("s_waitcnt vmcnt(4)" ::: "memory");
        __builtin_amdgcn_s_barrier();
        STEP_CORE(t1, pfB, pfA);
        asm volatile("s_waitcnt vmcnt(4)" ::: "memory");
        __builtin_amdgcn_s_barrier();
        STEP_CORE(t1 + 1, pfA, pfB);
    }
    // ---- step 15 ----
    asm volatile("s_waitcnt vmcnt(0)" ::: "memory");
    __builtin_amdgcn_s_barrier();
    STEP_CORE(15, pfB, pfA);
    // ---- drain: PV(15) ----
    {
        const int bP_ = (15 & 3) * 8192;
        PV_HALF(bP_, 0, pfB);
        PV_HALF(bP_, 1, pfB);
    }

    float* Op = Opart + ((size_t)(sp * NHEAD + h) * S_LEN + q0) * DK;
#pragma unroll
    for (int qc = 0; qc < 2; ++qc)
#pragma unroll
        for (int vc = 0; vc < 2; ++vc)
#pragma unroll
            for (int reg = 0; reg < 16; ++reg) {
                int q = qc * 32 + (reg & 3) + 8 * (reg >> 2) + 4 * lh;
                Op[(size_t)q * DK + vc * 32 + l31] = oacc[qc][vc][reg];
            }
    float zloc = z0 + z1;
#pragma unroll
    for (int off = 32; off > 0; off >>= 1) zloc += __shfl_xor(zloc, off, 64);
    if (l == 0) atomicAdd(Z, zloc);
}

// ---------------- split reduction: sum partials -> bf16 concat ----------------
__global__ __launch_bounds__(256) void reduce_o_kernel(
    const float* __restrict__ Opart, unsigned short* __restrict__ cc) {
    const int HSV = NHEAD * S_LEN * DK;
    int i = blockIdx.x * blockDim.x + threadIdx.x;
    if (i * 4 >= HSV) return;
    f32x4 s = {};
#pragma unroll
    for (int sp = 0; sp < SPLIT; ++sp) {
        f32x4 v = *reinterpret_cast<const f32x4*>(&Opart[(size_t)sp * HSV + i * 4]);
        s += v;
    }
    int e = i * 4;
    int h = e / (S_LEN * DK);
    int rem = e - h * (S_LEN * DK);
    int srow = rem / DK;
    int v = rem - srow * DK;
    ushort4 o4;
    o4.x = f2bf(s[0]); o4.y = f2bf(s[1]); o4.z = f2bf(s[2]); o4.w = f2bf(s[3]);
    *reinterpret_cast<ushort4*>(&cc[srow * DMODEL + h * DK + v]) = o4;
}

// ---------------- launcher ----------------

extern "C" void kernel_launch(void* const* d_in, const int* in_sizes, int n_in,
                              void* d_out, int out_size, void* d_ws, size_t ws_size,
                              hipStream_t stream) {
    const float* emb = (const float*)d_in[0];
    const float* wq = (const float*)d_in[1];
    const float* wk = (const float*)d_in[2];
    const float* wv = (const float*)d_in[3];
    const float* wo = (const float*)d_in[4];
    float* out = (float*)d_out;
    char* ws = (char*)d_ws;
    unsigned short* embB = (unsigned short*)(ws);             // 4 MB (reused as VT)
    unsigned short* wqT  = (unsigned short*)(ws + 4194304);   // contiguous 3 x 512 KB
    unsigned short* wkT  = (unsigned short*)(ws + 4718592);
    unsigned short* wvT  = (unsigned short*)(ws + 5242880);
    unsigned short* woT  = (unsigned short*)(ws + 5767168);
    unsigned short* Qb   = (unsigned short*)(ws + 6291456);   // 4 MB each
    unsigned short* Kb   = (unsigned short*)(ws + 10485760);
    unsigned short* Vb   = (unsigned short*)(ws + 14680064);
    unsigned short* cc   = (unsigned short*)(ws + 18874368);  // 4 MB
    float* Z             = (float*)(ws + 23068672);
    float* Opart         = (float*)(ws + 23072768);           // 32 MB
    unsigned short* VT   = embB;  // embB dead after proj

    cast_bf16_kernel<<<2048, 256, 0, stream>>>(emb, embB, 524288, Z);
    transpose_qkv_kernel<<<dim3(8, 24), 256, 0, stream>>>(wq, wk, wv, wqT, wkT, wvT);
    transpose_wo_kernel<<<dim3(8, 8), 256, 0, stream>>>(wo, woT);
    proj_tiled_kernel<<<dim3(32, 12), 256, 0, stream>>>(embB, wqT, Qb, Kb, Vb);
    vt_kernel<<<dim3(64, 8), 256, 0, stream>>>(Vb, VT);
    attn_kernel<<<dim3(16, 8, SPLIT), 256, 0, stream>>>(Qb, Kb, VT, Opart, Z);
    reduce_o_kernel<<<2048, 256, 0, stream>>>(Opart, cc);
    out_tiled_kernel<<<dim3(32, 4), 256, 0, stream>>>(cc, woT, Z, out);
}